// Round 6
// baseline (207.690 us; speedup 1.0000x reference)
//
#include <hip/hip_runtime.h>

#define EPS   1e-5f
#define SLOPE 0.01f

// ---------------------------------------------------------------------------
// Workspace layout (float offsets). Total 20,287,424 floats = 81.1 MB.
// ---------------------------------------------------------------------------
#define WS_H1B  0L            // h1  bf16 NHWC (64,56,56,96)   (9633792 f)
#define WS_OFF  9633792L      // off f32 [n=12544][32]            401408
#define WS_S1   10035200L     // bn1 scale f32 [96]
#define WS_T1   10035296L     // bn1 bias  f32 [96]
#define WS_T2   10035392L     // fused dcn_b+bn2 bias f32 [768]
#define WS_SB   10036160L     // S   bf16 [n=12544][k=1536]    (9633792 f)
#define WS_WTB  19669952L     // Wtb bf16 [oc=768][k=1536]      (589824 f)
#define WS_WOB  20259776L     // Wob bf16 [oc=32][k=1536]        (24576 f)
#define WS_W1B  20284352L     // W1b bf16 [ks=2][oc=96][kl=32]    (3072 f)

__device__ __forceinline__ unsigned short f2bf(float f) {
    unsigned int u = __builtin_bit_cast(unsigned int, f);
    u += 0x7fffu + ((u >> 16) & 1u);
    return (unsigned short)(u >> 16);
}
__device__ __forceinline__ float bf2f(unsigned short u) {
    unsigned int t = ((unsigned int)u) << 16;
    return __builtin_bit_cast(float, t);
}

typedef __attribute__((ext_vector_type(4))) unsigned short ushort4v;
typedef __attribute__((ext_vector_type(8))) unsigned short ushort8v;
typedef __attribute__((ext_vector_type(8))) short bf16x8;
typedef __attribute__((ext_vector_type(4))) float floatx4;

__device__ __forceinline__ floatx4 mfma16(bf16x8 a, bf16x8 b, floatx4 c) {
    return __builtin_amdgcn_mfma_f32_16x16x32_bf16(a, b, c, 0, 0, 0);
}

// LDS pointer type (32-bit AS3) + inline-asm ds_read_b128 the compiler's
// alias analysis can't see (so it cannot insert its own vmcnt drains --
// ordering is handled by OUR vmcnt/lgkmcnt asm + barriers; rule #18).
// PROVEN r5: this removed the compiler drain, k4 60.3 -> 50.5 us.
typedef __attribute__((address_space(3))) unsigned short lds_us;
__device__ __forceinline__ bf16x8 ldsr(const lds_us* p) {
    bf16x8 r;
    asm volatile("ds_read_b128 %0, %1" : "=&v"(r) : "v"(p));
    return r;
}

// ---------------------------------------------------------------------------
// K0: weight prep, transpose-via-LDS for coalescing.
// blk <800: Wtb/Wob transpose. blk==800: W1b/s1/t1/t2. blk>800 (392 blocks):
// zero the atomic `off` buffer (folds the hipMemsetAsync dispatch away).
// ---------------------------------------------------------------------------
__global__ __launch_bounds__(256) void k0_prep(
    const float* __restrict__ stem_w, const float* __restrict__ stem_b,
    const float* __restrict__ bn1_g,  const float* __restrict__ bn1_b,
    const float* __restrict__ bn1_m,  const float* __restrict__ bn1_v,
    const float* __restrict__ off_w,  const float* __restrict__ dcn_w,
    const float* __restrict__ dcn_b,  const float* __restrict__ bn2_g,
    const float* __restrict__ bn2_b,  const float* __restrict__ bn2_m,
    const float* __restrict__ bn2_v,  float* __restrict__ ws)
{
    const int tid = threadIdx.x;
    const int blk = blockIdx.x;
    unsigned short* Wtb = (unsigned short*)(ws + WS_WTB);
    unsigned short* Wob = (unsigned short*)(ws + WS_WOB);
    unsigned short* W1b = (unsigned short*)(ws + WS_W1B);

    if (blk < 800) {
        __shared__ float row[1536];
        const int oc = (blk < 768) ? blk : blk - 768;
        const float* src = (blk < 768) ? (dcn_w + (long)oc * 1536)
                                       : (off_w + (long)oc * 1536);
        for (int i = tid; i < 1536; i += 256) row[i] = src[i];
        float sc = 1.f;
        if (blk < 768) sc = bn2_g[oc] * rsqrtf(bn2_v[oc] + EPS);
        __syncthreads();
        if (tid < 192) {
            int k0 = tid * 8;
            ushort8v o;
#pragma unroll
            for (int t = 0; t < 8; t++) {
                int k = k0 + t;
                int kk = k / 96, c = k % 96;      // k = kk*96 + c
                ((unsigned short*)&o)[t] = f2bf(row[c * 16 + kk] * sc);
            }
            unsigned short* dst = (blk < 768) ? (Wtb + (long)oc * 1536 + k0)
                                              : (Wob + (long)oc * 1536 + k0);
            *(ushort8v*)dst = o;
        }
    } else if (blk == 800) {
        for (int i = tid; i < 6144; i += 256) {
            int ks = i / 3072, rr = i % 3072;
            int oc = rr >> 5, kl = rr & 31;
            int k = ks * 32 + kl;
            W1b[i] = f2bf(k < 48 ? stem_w[oc * 48 + k] : 0.f);
        }
        if (tid < 96) {
            float s = bn1_g[tid] * rsqrtf(bn1_v[tid] + EPS);
            ws[WS_S1 + tid] = s;
            ws[WS_T1 + tid] = stem_b[tid] * s + bn1_b[tid] - bn1_m[tid] * s;
        }
        for (int i = tid; i < 768; i += 256) {
            float inv2 = bn2_g[i] * rsqrtf(bn2_v[i] + EPS);
            ws[WS_T2 + i] = dcn_b[i] * inv2 + bn2_b[i] - bn2_m[i] * inv2;
        }
    } else {
        // zero off: 392 blocks x 256 thr x 4 f = 401408 floats exactly
        long i = (long)(blk - 801) * 1024 + tid * 4;
        float4 z; z.x = 0.f; z.y = 0.f; z.z = 0.f; z.w = 0.f;
        *(float4*)&ws[WS_OFF + i] = z;
    }
}

// ---------------------------------------------------------------------------
// K1: stem conv as bf16 MFMA GEMM, coalesced staging + LDS-repacked stores.
// ---------------------------------------------------------------------------
__global__ __launch_bounds__(256) void k1_stem_mfma(
    const float* __restrict__ x, const unsigned short* __restrict__ W1b,
    const float* __restrict__ s1, const float* __restrict__ t1,
    unsigned short* __restrict__ h1)
{
    const int tid  = threadIdx.x;
    const int wave = tid >> 6, lane = tid & 63;
    const int m = lane & 15, quad = lane >> 4;
    const int p0 = blockIdx.x * 128;

    __shared__ unsigned short sm[14336];   // 28672 B
    unsigned short* sA = sm;               // [2][128][32]
    unsigned short* sB = sm + 8192;        // [2][96][32]

#pragma unroll
    for (int i = 0; i < 3; i++) {
        int inst = wave * 3 + i;
        const unsigned short* g = W1b + inst * 512 + lane * 8;
        __builtin_amdgcn_global_load_lds(
            (const __attribute__((address_space(1))) void*)g,
            (__attribute__((address_space(3))) void*)(sB + inst * 512), 16, 0, 0);
    }
    {
        int r = tid >> 1, off = 16 + (tid & 1) * 8;
        *(ushort8v*)&sA[4096 + r * 32 + off] = (ushort8v)0;
    }
#pragma unroll
    for (int i = 0; i < 6; i++) {
        int unit = i * 256 + tid;
        int r = unit & 127, s = unit >> 7;
        int ci = s >> 2, kh = s & 3;
        int p = p0 + r;
        int b = p / 3136, rem = p % 3136;
        int oy = rem / 56, ox = rem % 56;
        float4 v = *(const float4*)&x[((long)((b * 3 + ci) * 224 + oy * 4 + kh)) * 224 + ox * 4];
        ushort4v hv;
        hv.x = f2bf(v.x); hv.y = f2bf(v.y); hv.z = f2bf(v.z); hv.w = f2bf(v.w);
        int k0i = ci * 16 + kh * 4;
        *(ushort4v*)&sA[(k0i >> 5) * 4096 + r * 32 + (k0i & 31)] = hv;
    }
    __syncthreads();

    bf16x8 bfv[6][2], af[2][2];
#pragma unroll
    for (int j = 0; j < 6; j++)
#pragma unroll
        for (int ks = 0; ks < 2; ks++)
            bfv[j][ks] = *(const bf16x8*)&sB[ks * 3072 + (j * 16 + m) * 32 + quad * 8];
#pragma unroll
    for (int rt = 0; rt < 2; rt++)
#pragma unroll
        for (int ks = 0; ks < 2; ks++)
            af[rt][ks] = *(const bf16x8*)&sA[ks * 4096 + (wave * 32 + rt * 16 + m) * 32 + quad * 8];

    floatx4 acc[2][6];
#pragma unroll
    for (int rt = 0; rt < 2; rt++)
#pragma unroll
        for (int j = 0; j < 6; j++) {
            floatx4 a = (floatx4)0.f;
            a = __builtin_amdgcn_mfma_f32_16x16x32_bf16(af[rt][0], bfv[j][0], a, 0, 0, 0);
            a = __builtin_amdgcn_mfma_f32_16x16x32_bf16(af[rt][1], bfv[j][1], a, 0, 0, 0);
            acc[rt][j] = a;
        }

    __syncthreads();
#pragma unroll
    for (int j = 0; j < 6; j++) {
        int c = j * 16 + m;
        float sc = s1[c], bi = t1[c];
#pragma unroll
        for (int rt = 0; rt < 2; rt++)
#pragma unroll
            for (int r = 0; r < 4; r++) {
                int row = wave * 32 + rt * 16 + quad * 4 + r;
                float v = acc[rt][j][r] * sc + bi;
                v = v >= 0.f ? v : SLOPE * v;
                sm[row * 96 + c] = f2bf(v);
            }
    }
    __syncthreads();
#pragma unroll
    for (int i = 0; i < 6; i++) {
        int idx = (i * 256 + tid) * 8;
        *(ushort8v*)&h1[(long)p0 * 96 + idx] = *(const ushort8v*)&sm[idx];
    }
}

// ---------------------------------------------------------------------------
// K2: offset conv, K-split x4 across blocks + dbuf prefetch + atomic reduce.
// ---------------------------------------------------------------------------
__global__ __launch_bounds__(256) void k2_mfma(
    const unsigned short* __restrict__ h1,   // bf16 NHWC
    const unsigned short* __restrict__ Wob,  // [32][1536] bf16
    const float* __restrict__ off_b, float* __restrict__ off)
{
    const int tid  = threadIdx.x;
    const int wave = tid >> 6, lane = tid & 63;
    const int m = lane & 15, quad = lane >> 4;
    const int nt = blockIdx.x % 98, ks = blockIdx.x / 98;
    const int n0 = nt * 128;

    __shared__ unsigned short sA[2][4096];   // [buf][128*32]
    __shared__ unsigned short sB[2][1024];   // [buf][32*32]

    const int skoff = (lane & 3) * 8;
    int n_a = n0 + wave * 32 + (lane >> 2);
    int n_b = n_a + 16;
    int ba = n_a / 196, pa = n_a % 196;
    int bb = n_b / 196, pb = n_b % 196;
    long pixa = ((long)(ba * 56 + (pa / 14) * 4) * 56 + (pa % 14) * 4);
    long pixb = ((long)(bb * 56 + (pb / 14) * 4) * 56 + (pb % 14) * 4);

    const unsigned short* gB = Wob + (long)(wave * 16 + (lane >> 2)) * 1536 + ks * 384 + skoff;
    const int lofA0 = (wave * 32) * 32;
    const int lofA1 = (wave * 32 + 16) * 32;
    const int lofB  = (wave * 16) * 32;

    auto issue = [&](int buf, int kt) {
        int khw = ks * 4 + kt / 3;
        int c0  = (kt % 3) * 32;
        int kh  = khw >> 2, kw = khw & 3;
        long eoff = (long)(kh * 56 + kw) * 96 + c0 + skoff;
        __builtin_amdgcn_global_load_lds(
            (const __attribute__((address_space(1))) void*)(h1 + pixa * 96 + eoff),
            (__attribute__((address_space(3))) void*)&sA[buf][lofA0], 16, 0, 0);
        __builtin_amdgcn_global_load_lds(
            (const __attribute__((address_space(1))) void*)(h1 + pixb * 96 + eoff),
            (__attribute__((address_space(3))) void*)&sA[buf][lofA1], 16, 0, 0);
        if (wave < 2)
            __builtin_amdgcn_global_load_lds(
                (const __attribute__((address_space(1))) void*)(gB + kt * 32),
                (__attribute__((address_space(3))) void*)&sB[buf][lofB], 16, 0, 0);
    };

    floatx4 acc[2][2];
#pragma unroll
    for (int i = 0; i < 2; i++)
#pragma unroll
        for (int j = 0; j < 2; j++) acc[i][j] = (floatx4)0.f;

    issue(0, 0);
    for (int kt = 0; kt < 12; ++kt) {
        __syncthreads();                       // drains tile kt's loads
        if (kt < 11) issue((kt + 1) & 1, kt + 1);
        const unsigned short* bufA = sA[kt & 1];
        const unsigned short* bufB = sB[kt & 1];
        bf16x8 af[2], bfr[2];
#pragma unroll
        for (int i = 0; i < 2; i++)
            af[i] = *(const bf16x8*)&bufA[(wave * 32 + i * 16 + m) * 32 + quad * 8];
#pragma unroll
        for (int j = 0; j < 2; j++)
            bfr[j] = *(const bf16x8*)&bufB[(j * 16 + m) * 32 + quad * 8];
#pragma unroll
        for (int i = 0; i < 2; i++)
#pragma unroll
            for (int j = 0; j < 2; j++)
                acc[i][j] = __builtin_amdgcn_mfma_f32_16x16x32_bf16(
                    af[i], bfr[j], acc[i][j], 0, 0, 0);
    }

    float tb[2];
#pragma unroll
    for (int j = 0; j < 2; j++) tb[j] = (ks == 0) ? off_b[j * 16 + m] : 0.f;
#pragma unroll
    for (int i = 0; i < 2; i++)
#pragma unroll
        for (int r = 0; r < 4; r++) {
            long n = n0 + wave * 32 + i * 16 + quad * 4 + r;
#pragma unroll
            for (int j = 0; j < 2; j++)
                atomicAdd(&off[n * 32 + j * 16 + m], acc[i][j][r] + tb[j]);
        }
}

// ---------------------------------------------------------------------------
// K3: bilinear sampling from bf16 h1 -> S bf16 [n][k], k = kk*96 + c.
// ---------------------------------------------------------------------------
__global__ __launch_bounds__(384) void k3_sample(
    const unsigned short* __restrict__ h1, const float* __restrict__ off,
    unsigned short* __restrict__ S)
{
    const int p = blockIdx.x;     // 0..195
    const int b = blockIdx.y;     // 0..63
    const int y = p / 14, xo = p % 14;
    const int tid = threadIdx.x;
    const int c4 = tid % 24, kk = tid / 24;
    const int kh = kk >> 2, kw = kk & 3;

    const float* ob = off + ((long)(b * 196 + p)) * 32;
    float dy = ob[kk * 2];
    float dx = ob[kk * 2 + 1];

    float py = (float)(y * 4 + kh) + dy;
    float px = (float)(xo * 4 + kw) + dx;
    float y0f = floorf(py), x0f = floorf(px);
    float wy = py - y0f, wx = px - x0f;
    int y0 = (int)y0f, x0 = (int)x0f;
    int y1 = y0 + 1,  x1 = x0 + 1;

    float my0 = (y0 >= 0 && y0 < 56) ? 1.f : 0.f;
    float my1 = (y1 >= 0 && y1 < 56) ? 1.f : 0.f;
    float mx0 = (x0 >= 0 && x0 < 56) ? 1.f : 0.f;
    float mx1 = (x1 >= 0 && x1 < 56) ? 1.f : 0.f;
    int y0c = min(max(y0, 0), 55), y1c = min(max(y1, 0), 55);
    int x0c = min(max(x0, 0), 55), x1c = min(max(x1, 0), 55);

    const unsigned short* hb = h1 + (long)b * 56 * 56 * 96 + c4 * 4;
    ushort4v v00 = *(const ushort4v*)&hb[(y0c * 56 + x0c) * 96];
    ushort4v v01 = *(const ushort4v*)&hb[(y0c * 56 + x1c) * 96];
    ushort4v v10 = *(const ushort4v*)&hb[(y1c * 56 + x0c) * 96];
    ushort4v v11 = *(const ushort4v*)&hb[(y1c * 56 + x1c) * 96];

    float w00 = my0 * mx0 * (1.f - wy) * (1.f - wx);
    float w01 = my0 * mx1 * (1.f - wy) * wx;
    float w10 = my1 * mx0 * wy * (1.f - wx);
    float w11 = my1 * mx1 * wy * wx;

    ushort4v rr;
#pragma unroll
    for (int c = 0; c < 4; c++) {
        float v = bf2f(((unsigned short*)&v00)[c]) * w00
                + bf2f(((unsigned short*)&v01)[c]) * w01
                + bf2f(((unsigned short*)&v10)[c]) * w10
                + bf2f(((unsigned short*)&v11)[c]) * w11;
        ((unsigned short*)&rr)[c] = f2bf(v);
    }

    long n = (long)b * 196 + p;
    *(ushort4v*)&S[n * 1536 + kk * 96 + c4 * 4] = rr;
}

// ---------------------------------------------------------------------------
// K4: bf16 MFMA GEMM  C[n][oc] = S[n][k] * Wtb[oc][k]^T  (N=12544,M=768,K=1536)
// r5's PROVEN asm 4-phase counted-vmcnt schedule, re-tiled for FULL CU use:
// r5 counters showed Occupancy 10.4% -- 147 blocks on 256 CUs left 43% of
// the machine idle. Now BM=BN=128, 256 threads (4 waves, 2x2, per-wave
// 64x64), LDS 64KB -> 2 blocks/CU concurrent, grid 98x6 = 588 blocks
// (~2.3/CU). Cross-block TLP (m114) hides each block's barrier stalls.
// Schedule per K-tile (BK=64, 24 tiles) unchanged from r5:
//   4 chunks (A-lo/A-hi/B-lo/B-hi, 2 gload_lds per wave each);
//   phase 0: CH0(t+1), vmcnt(2) [tile t landed, t+1 chunk0 airborne],
//            barrier, asm ds_reads (bfr[4][2] + A i=0), lgkmcnt(0),
//            sched_barrier, setprio(1) 8 MFMA setprio(0), barrier;
//   phases 1-3: A-reads i=p, CHp(t+1), barrier, lgkmcnt(0), MFMA, barrier.
// All K-loop LDS reads are inline asm (compiler cannot re-insert vmcnt(0)
// drains -- r5 proved this is worth 16%). XOR-swizzle slot^=(row&7) on
// staging source + read addr: conflict-free (verified: BANK_CONFLICT==0).
// XCD swizzle bijective for 588 (q=73, r=4); consecutive works = 6 oc-tiles
// of one n-tile -> S rows reused within an XCD's L2.
// ---------------------------------------------------------------------------
__global__ __launch_bounds__(256, 2) void k4_gemm_mfma(
    const unsigned short* __restrict__ S,    // [12544][1536] bf16
    const unsigned short* __restrict__ Wtb,  // [768][1536]  bf16 (B^T, scaled)
    const float* __restrict__ t2, float* __restrict__ out)
{
    const int tid  = threadIdx.x;
    const int wave = tid >> 6, lane = tid & 63;

    // bijective XCD swizzle for nwg=588: q=73, r=4
    int lid = blockIdx.x;
    int xcd = lid & 7, pos = lid >> 3;
    int work = ((xcd < 4) ? xcd * 74 : 296 + (xcd - 4) * 73) + pos;
    const int n0  = (work / 6) * 128;
    const int oc0 = (work % 6) * 128;

    const int wr = wave >> 1, wc = wave & 1;     // 2 x 2 wave grid
    const int m = lane & 15, quad = lane >> 4;

    __shared__ unsigned short sA[2][8192];       // [buf][128 rows * 64 k] 32KB
    __shared__ unsigned short sB[2][8192];       // [buf][128 rows * 64 k] 32KB

    // staging: one gload_lds = 64 lanes x 16B = 8 rows of 128B.
    // lane -> row lr = lane>>3, slot ls = lane&7; LDS slot s of row r holds
    // logical k-chunk s^(r&7); source fetches chunk ls^lr.
    const int lr = lane >> 3;
    const int ls = lane & 7;
    const int swzk = ((ls ^ lr) * 8);            // element offset in 64-k row

    // 4 chunks/K-tile: A rows [0,64), [64,128), B rows [0,64), [64,128).
    // chunk = 8KB = 8 instrs = 2 per wave (rows wave*16 + {0,8}).
    const unsigned short* pA0  = S   + (long)(n0  + wave * 16 + lr) * 1536 + swzk;
    const unsigned short* pA0b = pA0 + 8 * 1536;
    const unsigned short* pA1  = pA0 + 64 * 1536;
    const unsigned short* pA1b = pA1 + 8 * 1536;
    const unsigned short* pB0  = Wtb + (long)(oc0 + wave * 16 + lr) * 1536 + swzk;
    const unsigned short* pB0b = pB0 + 8 * 1536;
    const unsigned short* pB1  = pB0 + 64 * 1536;
    const unsigned short* pB1b = pB1 + 8 * 1536;

    const int ldsO0  = wave * 1024;              // (wave*16)*64
    const int ldsO0b = wave * 1024 + 512;        // (wave*16+8)*64
    const int ldsO1  = 4096 + wave * 1024;       // (64+wave*16)*64
    const int ldsO1b = 4096 + wave * 1024 + 512;

    auto gl = [&](const unsigned short* g, unsigned short* l) {
        __builtin_amdgcn_global_load_lds(
            (const __attribute__((address_space(1))) void*)g,
            (__attribute__((address_space(3))) void*)l, 16, 0, 0);
    };
    auto CH0 = [&](int nb) { gl(pA0, &sA[nb][ldsO0]); gl(pA0b, &sA[nb][ldsO0b]); pA0 += 64; pA0b += 64; };
    auto CH1 = [&](int nb) { gl(pA1, &sA[nb][ldsO1]); gl(pA1b, &sA[nb][ldsO1b]); pA1 += 64; pA1b += 64; };
    auto CH2 = [&](int nb) { gl(pB0, &sB[nb][ldsO0]); gl(pB0b, &sB[nb][ldsO0b]); pB0 += 64; pB0b += 64; };
    auto CH3 = [&](int nb) { gl(pB1, &sB[nb][ldsO1]); gl(pB1b, &sB[nb][ldsO1b]); pB1 += 64; pB1b += 64; };

    // per-thread fragment addressing (swizzled read): logical chunk
    // (ks*4+quad) of row r lives at slot ^(r&7); r&7 == m&7.
    const int rowA = (wr * 64 + m) * 64;
    const int rowB = (wc * 64 + m) * 64;
    const int x0 = ((quad)     ^ (m & 7)) * 8;   // ks = 0
    const int x1 = ((quad + 4) ^ (m & 7)) * 8;   // ks = 1

    floatx4 acc[4][4];
#pragma unroll
    for (int i = 0; i < 4; i++)
#pragma unroll
        for (int j = 0; j < 4; j++) acc[i][j] = (floatx4)0.f;

    // prologue: stage tile 0 fully (8 instr/wave in flight)
    CH0(0); CH1(0); CH2(0); CH3(0);

#define MFMA_PHASE(I, A0, A1)                                                 \
    __builtin_amdgcn_s_setprio(1);                                            \
    _Pragma("unroll")                                                         \
    for (int j = 0; j < 4; j++) {                                             \
        acc[(I)][j] = mfma16(A0, bfr[j][0], acc[(I)][j]);                     \
        acc[(I)][j] = mfma16(A1, bfr[j][1], acc[(I)][j]);                     \
    }                                                                         \
    __builtin_amdgcn_s_setprio(0);

    for (int t = 0; t < 24; ++t) {
        const int cb = t & 1, nb = cb ^ 1;
        const bool pf = (t < 23);
        const lds_us* pAk0 = (const lds_us*)(sA[cb]) + rowA + x0;
        const lds_us* pAk1 = (const lds_us*)(sA[cb]) + rowA + x1;
        const lds_us* pBk0 = (const lds_us*)(sB[cb]) + rowB + x0;
        const lds_us* pBk1 = (const lds_us*)(sB[cb]) + rowB + x1;

        // ---- phase 0: counted-vmcnt wait for tile t, issue t+1 chunk 0
        if (pf) {
            CH0(nb);
            asm volatile("s_waitcnt vmcnt(2)" ::: "memory");
        } else {
            asm volatile("s_waitcnt vmcnt(0)" ::: "memory");
        }
        __builtin_amdgcn_sched_barrier(0);
        __builtin_amdgcn_s_barrier();            // all waves' tile-t loads landed

        bf16x8 bfr[4][2];
#pragma unroll
        for (int j = 0; j < 4; j++) {
            bfr[j][0] = ldsr(pBk0 + j * 1024);
            bfr[j][1] = ldsr(pBk1 + j * 1024);
        }
        bf16x8 a0 = ldsr(pAk0);
        bf16x8 a1 = ldsr(pAk1);
        asm volatile("s_waitcnt lgkmcnt(0)" ::: "memory");
        __builtin_amdgcn_sched_barrier(0);
        MFMA_PHASE(0, a0, a1)
        __builtin_amdgcn_s_barrier();

        // ---- phase 1 (i=1), prefetch chunk 1
        a0 = ldsr(pAk0 + 1024);
        a1 = ldsr(pAk1 + 1024);
        if (pf) CH1(nb);
        __builtin_amdgcn_s_barrier();
        asm volatile("s_waitcnt lgkmcnt(0)" ::: "memory");
        __builtin_amdgcn_sched_barrier(0);
        MFMA_PHASE(1, a0, a1)
        __builtin_amdgcn_s_barrier();

        // ---- phase 2 (i=2), prefetch chunk 2
        a0 = ldsr(pAk0 + 2 * 1024);
        a1 = ldsr(pAk1 + 2 * 1024);
        if (pf) CH2(nb);
        __builtin_amdgcn_s_barrier();
        asm volatile("s_waitcnt lgkmcnt(0)" ::: "memory");
        __builtin_amdgcn_sched_barrier(0);
        MFMA_PHASE(2, a0, a1)
        __builtin_amdgcn_s_barrier();

        // ---- phase 3 (i=3), prefetch chunk 3
        a0 = ldsr(pAk0 + 3 * 1024);
        a1 = ldsr(pAk1 + 3 * 1024);
        if (pf) CH3(nb);
        __builtin_amdgcn_s_barrier();
        asm volatile("s_waitcnt lgkmcnt(0)" ::: "memory");
        __builtin_amdgcn_sched_barrier(0);
        MFMA_PHASE(3, a0, a1)
        __builtin_amdgcn_s_barrier();
    }
#undef MFMA_PHASE

    // epilogue: bias + leaky-relu + store (f32, coalesced over m)
    float tb[4];
#pragma unroll
    for (int j = 0; j < 4; j++) tb[j] = t2[oc0 + wc * 64 + j * 16 + m];
#pragma unroll
    for (int i = 0; i < 4; i++) {
#pragma unroll
        for (int r = 0; r < 4; r++) {
            long n = n0 + wr * 64 + i * 16 + quad * 4 + r;
            float* orow = out + n * 768 + oc0 + wc * 64 + m;
#pragma unroll
            for (int j = 0; j < 4; j++) {
                float v = acc[i][j][r] + tb[j];
                orow[j * 16] = v >= 0.f ? v : SLOPE * v;
            }
        }
    }
}

// ---------------------------------------------------------------------------
extern "C" void kernel_launch(void* const* d_in, const int* in_sizes, int n_in,
                              void* d_out, int out_size, void* d_ws, size_t ws_size,
                              hipStream_t stream)
{
    const float* x      = (const float*)d_in[0];
    const float* stem_w = (const float*)d_in[1];
    const float* stem_b = (const float*)d_in[2];
    const float* bn1_g  = (const float*)d_in[3];
    const float* bn1_b  = (const float*)d_in[4];
    const float* bn1_m  = (const float*)d_in[5];
    const float* bn1_v  = (const float*)d_in[6];
    const float* off_w  = (const float*)d_in[7];
    const float* off_b  = (const float*)d_in[8];
    const float* dcn_w  = (const float*)d_in[9];
    const float* dcn_b  = (const float*)d_in[10];
    const float* bn2_g  = (const float*)d_in[11];
    const float* bn2_b  = (const float*)d_in[12];
    const float* bn2_m  = (const float*)d_in[13];
    const float* bn2_v  = (const float*)d_in[14];

    float* ws  = (float*)d_ws;        // needs 81.2 MB
    float* out = (float*)d_out;

    unsigned short* h1  = (unsigned short*)(ws + WS_H1B);
    float* off = ws + WS_OFF;
    float* s1  = ws + WS_S1;
    float* t1  = ws + WS_T1;
    float* t2  = ws + WS_T2;
    unsigned short* Sb  = (unsigned short*)(ws + WS_SB);
    unsigned short* Wtb = (unsigned short*)(ws + WS_WTB);
    unsigned short* Wob = (unsigned short*)(ws + WS_WOB);
    unsigned short* W1b = (unsigned short*)(ws + WS_W1B);

    // k0 also zeroes the atomic `off` buffer (blocks 801..1192)
    k0_prep<<<1193, 256, 0, stream>>>(stem_w, stem_b, bn1_g, bn1_b, bn1_m, bn1_v,
                                      off_w, dcn_w, dcn_b, bn2_g, bn2_b, bn2_m,
                                      bn2_v, ws);
    k1_stem_mfma<<<1568, 256, 0, stream>>>(x, W1b, s1, t1, h1);
    k2_mfma<<<392, 256, 0, stream>>>(h1, Wob, off_b, off);
    k3_sample<<<dim3(196, 64), 384, 0, stream>>>(h1, off, Sb);
    k4_gemm_mfma<<<588, 256, 0, stream>>>(Sb, Wtb, t2, out);
}

// Round 7
// 195.683 us; speedup vs baseline: 1.0614x; 1.0614x over previous
//
#include <hip/hip_runtime.h>

#define EPS   1e-5f
#define SLOPE 0.01f

// ---------------------------------------------------------------------------
// Workspace layout (float offsets). Total 20,287,424 floats = 81.1 MB.
// ---------------------------------------------------------------------------
#define WS_H1B  0L            // h1  bf16 NHWC (64,56,56,96)   (9633792 f)
#define WS_OFF  9633792L      // off f32 [n=12544][32]            401408
#define WS_S1   10035200L     // bn1 scale f32 [96]
#define WS_T1   10035296L     // bn1 bias  f32 [96]
#define WS_T2   10035392L     // fused dcn_b+bn2 bias f32 [768]
#define WS_SB   10036160L     // S   bf16 [n=12544][k=1536]    (9633792 f)
#define WS_WTB  19669952L     // Wtb bf16 [oc=768][k=1536]      (589824 f)
#define WS_WOB  20259776L     // Wob bf16 [oc=32][k=1536]        (24576 f)
#define WS_W1B  20284352L     // W1b bf16 [ks=2][oc=96][kl=32]    (3072 f)

__device__ __forceinline__ unsigned short f2bf(float f) {
    unsigned int u = __builtin_bit_cast(unsigned int, f);
    u += 0x7fffu + ((u >> 16) & 1u);
    return (unsigned short)(u >> 16);
}
__device__ __forceinline__ float bf2f(unsigned short u) {
    unsigned int t = ((unsigned int)u) << 16;
    return __builtin_bit_cast(float, t);
}

typedef __attribute__((ext_vector_type(4))) unsigned short ushort4v;
typedef __attribute__((ext_vector_type(8))) unsigned short ushort8v;
typedef __attribute__((ext_vector_type(8))) short bf16x8;
typedef __attribute__((ext_vector_type(4))) float floatx4;

__device__ __forceinline__ floatx4 mfma16(bf16x8 a, bf16x8 b, floatx4 c) {
    return __builtin_amdgcn_mfma_f32_16x16x32_bf16(a, b, c, 0, 0, 0);
}

// LDS pointer type (32-bit AS3) + inline-asm ds_read_b128 the compiler's
// alias analysis can't see (so it cannot insert its own vmcnt drains --
// ordering is handled by OUR vmcnt/lgkmcnt asm + barriers; rule #18).
// PROVEN r5: this removed the compiler drain, k4 60.3 -> 50.5 us.
typedef __attribute__((address_space(3))) unsigned short lds_us;
__device__ __forceinline__ bf16x8 ldsr(const lds_us* p) {
    bf16x8 r;
    asm volatile("ds_read_b128 %0, %1" : "=&v"(r) : "v"(p));
    return r;
}

// ---------------------------------------------------------------------------
// K0: weight prep, transpose-via-LDS for coalescing.
// blk <800: Wtb/Wob transpose. blk==800: W1b/s1/t1/t2. blk>800 (392 blocks):
// zero the atomic `off` buffer (folds the hipMemsetAsync dispatch away).
// ---------------------------------------------------------------------------
__global__ __launch_bounds__(256) void k0_prep(
    const float* __restrict__ stem_w, const float* __restrict__ stem_b,
    const float* __restrict__ bn1_g,  const float* __restrict__ bn1_b,
    const float* __restrict__ bn1_m,  const float* __restrict__ bn1_v,
    const float* __restrict__ off_w,  const float* __restrict__ dcn_w,
    const float* __restrict__ dcn_b,  const float* __restrict__ bn2_g,
    const float* __restrict__ bn2_b,  const float* __restrict__ bn2_m,
    const float* __restrict__ bn2_v,  float* __restrict__ ws)
{
    const int tid = threadIdx.x;
    const int blk = blockIdx.x;
    unsigned short* Wtb = (unsigned short*)(ws + WS_WTB);
    unsigned short* Wob = (unsigned short*)(ws + WS_WOB);
    unsigned short* W1b = (unsigned short*)(ws + WS_W1B);

    if (blk < 800) {
        __shared__ float row[1536];
        const int oc = (blk < 768) ? blk : blk - 768;
        const float* src = (blk < 768) ? (dcn_w + (long)oc * 1536)
                                       : (off_w + (long)oc * 1536);
        for (int i = tid; i < 1536; i += 256) row[i] = src[i];
        float sc = 1.f;
        if (blk < 768) sc = bn2_g[oc] * rsqrtf(bn2_v[oc] + EPS);
        __syncthreads();
        if (tid < 192) {
            int k0 = tid * 8;
            ushort8v o;
#pragma unroll
            for (int t = 0; t < 8; t++) {
                int k = k0 + t;
                int kk = k / 96, c = k % 96;      // k = kk*96 + c
                ((unsigned short*)&o)[t] = f2bf(row[c * 16 + kk] * sc);
            }
            unsigned short* dst = (blk < 768) ? (Wtb + (long)oc * 1536 + k0)
                                              : (Wob + (long)oc * 1536 + k0);
            *(ushort8v*)dst = o;
        }
    } else if (blk == 800) {
        for (int i = tid; i < 6144; i += 256) {
            int ks = i / 3072, rr = i % 3072;
            int oc = rr >> 5, kl = rr & 31;
            int k = ks * 32 + kl;
            W1b[i] = f2bf(k < 48 ? stem_w[oc * 48 + k] : 0.f);
        }
        if (tid < 96) {
            float s = bn1_g[tid] * rsqrtf(bn1_v[tid] + EPS);
            ws[WS_S1 + tid] = s;
            ws[WS_T1 + tid] = stem_b[tid] * s + bn1_b[tid] - bn1_m[tid] * s;
        }
        for (int i = tid; i < 768; i += 256) {
            float inv2 = bn2_g[i] * rsqrtf(bn2_v[i] + EPS);
            ws[WS_T2 + i] = dcn_b[i] * inv2 + bn2_b[i] - bn2_m[i] * inv2;
        }
    } else {
        // zero off: 392 blocks x 256 thr x 4 f = 401408 floats exactly
        long i = (long)(blk - 801) * 1024 + tid * 4;
        float4 z; z.x = 0.f; z.y = 0.f; z.z = 0.f; z.w = 0.f;
        *(float4*)&ws[WS_OFF + i] = z;
    }
}

// ---------------------------------------------------------------------------
// K1: stem conv as bf16 MFMA GEMM, coalesced staging + LDS-repacked stores.
// ---------------------------------------------------------------------------
__global__ __launch_bounds__(256) void k1_stem_mfma(
    const float* __restrict__ x, const unsigned short* __restrict__ W1b,
    const float* __restrict__ s1, const float* __restrict__ t1,
    unsigned short* __restrict__ h1)
{
    const int tid  = threadIdx.x;
    const int wave = tid >> 6, lane = tid & 63;
    const int m = lane & 15, quad = lane >> 4;
    const int p0 = blockIdx.x * 128;

    __shared__ unsigned short sm[14336];   // 28672 B
    unsigned short* sA = sm;               // [2][128][32]
    unsigned short* sB = sm + 8192;        // [2][96][32]

#pragma unroll
    for (int i = 0; i < 3; i++) {
        int inst = wave * 3 + i;
        const unsigned short* g = W1b + inst * 512 + lane * 8;
        __builtin_amdgcn_global_load_lds(
            (const __attribute__((address_space(1))) void*)g,
            (__attribute__((address_space(3))) void*)(sB + inst * 512), 16, 0, 0);
    }
    {
        int r = tid >> 1, off = 16 + (tid & 1) * 8;
        *(ushort8v*)&sA[4096 + r * 32 + off] = (ushort8v)0;
    }
#pragma unroll
    for (int i = 0; i < 6; i++) {
        int unit = i * 256 + tid;
        int r = unit & 127, s = unit >> 7;
        int ci = s >> 2, kh = s & 3;
        int p = p0 + r;
        int b = p / 3136, rem = p % 3136;
        int oy = rem / 56, ox = rem % 56;
        float4 v = *(const float4*)&x[((long)((b * 3 + ci) * 224 + oy * 4 + kh)) * 224 + ox * 4];
        ushort4v hv;
        hv.x = f2bf(v.x); hv.y = f2bf(v.y); hv.z = f2bf(v.z); hv.w = f2bf(v.w);
        int k0i = ci * 16 + kh * 4;
        *(ushort4v*)&sA[(k0i >> 5) * 4096 + r * 32 + (k0i & 31)] = hv;
    }
    __syncthreads();

    bf16x8 bfv[6][2], af[2][2];
#pragma unroll
    for (int j = 0; j < 6; j++)
#pragma unroll
        for (int ks = 0; ks < 2; ks++)
            bfv[j][ks] = *(const bf16x8*)&sB[ks * 3072 + (j * 16 + m) * 32 + quad * 8];
#pragma unroll
    for (int rt = 0; rt < 2; rt++)
#pragma unroll
        for (int ks = 0; ks < 2; ks++)
            af[rt][ks] = *(const bf16x8*)&sA[ks * 4096 + (wave * 32 + rt * 16 + m) * 32 + quad * 8];

    floatx4 acc[2][6];
#pragma unroll
    for (int rt = 0; rt < 2; rt++)
#pragma unroll
        for (int j = 0; j < 6; j++) {
            floatx4 a = (floatx4)0.f;
            a = __builtin_amdgcn_mfma_f32_16x16x32_bf16(af[rt][0], bfv[j][0], a, 0, 0, 0);
            a = __builtin_amdgcn_mfma_f32_16x16x32_bf16(af[rt][1], bfv[j][1], a, 0, 0, 0);
            acc[rt][j] = a;
        }

    __syncthreads();
#pragma unroll
    for (int j = 0; j < 6; j++) {
        int c = j * 16 + m;
        float sc = s1[c], bi = t1[c];
#pragma unroll
        for (int rt = 0; rt < 2; rt++)
#pragma unroll
            for (int r = 0; r < 4; r++) {
                int row = wave * 32 + rt * 16 + quad * 4 + r;
                float v = acc[rt][j][r] * sc + bi;
                v = v >= 0.f ? v : SLOPE * v;
                sm[row * 96 + c] = f2bf(v);
            }
    }
    __syncthreads();
#pragma unroll
    for (int i = 0; i < 6; i++) {
        int idx = (i * 256 + tid) * 8;
        *(ushort8v*)&h1[(long)p0 * 96 + idx] = *(const ushort8v*)&sm[idx];
    }
}

// ---------------------------------------------------------------------------
// K2: offset conv, K-split x4 across blocks + dbuf prefetch + atomic reduce.
// ---------------------------------------------------------------------------
__global__ __launch_bounds__(256) void k2_mfma(
    const unsigned short* __restrict__ h1,   // bf16 NHWC
    const unsigned short* __restrict__ Wob,  // [32][1536] bf16
    const float* __restrict__ off_b, float* __restrict__ off)
{
    const int tid  = threadIdx.x;
    const int wave = tid >> 6, lane = tid & 63;
    const int m = lane & 15, quad = lane >> 4;
    const int nt = blockIdx.x % 98, ks = blockIdx.x / 98;
    const int n0 = nt * 128;

    __shared__ unsigned short sA[2][4096];   // [buf][128*32]
    __shared__ unsigned short sB[2][1024];   // [buf][32*32]

    const int skoff = (lane & 3) * 8;
    int n_a = n0 + wave * 32 + (lane >> 2);
    int n_b = n_a + 16;
    int ba = n_a / 196, pa = n_a % 196;
    int bb = n_b / 196, pb = n_b % 196;
    long pixa = ((long)(ba * 56 + (pa / 14) * 4) * 56 + (pa % 14) * 4);
    long pixb = ((long)(bb * 56 + (pb / 14) * 4) * 56 + (pb % 14) * 4);

    const unsigned short* gB = Wob + (long)(wave * 16 + (lane >> 2)) * 1536 + ks * 384 + skoff;
    const int lofA0 = (wave * 32) * 32;
    const int lofA1 = (wave * 32 + 16) * 32;
    const int lofB  = (wave * 16) * 32;

    auto issue = [&](int buf, int kt) {
        int khw = ks * 4 + kt / 3;
        int c0  = (kt % 3) * 32;
        int kh  = khw >> 2, kw = khw & 3;
        long eoff = (long)(kh * 56 + kw) * 96 + c0 + skoff;
        __builtin_amdgcn_global_load_lds(
            (const __attribute__((address_space(1))) void*)(h1 + pixa * 96 + eoff),
            (__attribute__((address_space(3))) void*)&sA[buf][lofA0], 16, 0, 0);
        __builtin_amdgcn_global_load_lds(
            (const __attribute__((address_space(1))) void*)(h1 + pixb * 96 + eoff),
            (__attribute__((address_space(3))) void*)&sA[buf][lofA1], 16, 0, 0);
        if (wave < 2)
            __builtin_amdgcn_global_load_lds(
                (const __attribute__((address_space(1))) void*)(gB + kt * 32),
                (__attribute__((address_space(3))) void*)&sB[buf][lofB], 16, 0, 0);
    };

    floatx4 acc[2][2];
#pragma unroll
    for (int i = 0; i < 2; i++)
#pragma unroll
        for (int j = 0; j < 2; j++) acc[i][j] = (floatx4)0.f;

    issue(0, 0);
    for (int kt = 0; kt < 12; ++kt) {
        __syncthreads();                       // drains tile kt's loads
        if (kt < 11) issue((kt + 1) & 1, kt + 1);
        const unsigned short* bufA = sA[kt & 1];
        const unsigned short* bufB = sB[kt & 1];
        bf16x8 af[2], bfr[2];
#pragma unroll
        for (int i = 0; i < 2; i++)
            af[i] = *(const bf16x8*)&bufA[(wave * 32 + i * 16 + m) * 32 + quad * 8];
#pragma unroll
        for (int j = 0; j < 2; j++)
            bfr[j] = *(const bf16x8*)&bufB[(j * 16 + m) * 32 + quad * 8];
#pragma unroll
        for (int i = 0; i < 2; i++)
#pragma unroll
            for (int j = 0; j < 2; j++)
                acc[i][j] = __builtin_amdgcn_mfma_f32_16x16x32_bf16(
                    af[i], bfr[j], acc[i][j], 0, 0, 0);
    }

    float tb[2];
#pragma unroll
    for (int j = 0; j < 2; j++) tb[j] = (ks == 0) ? off_b[j * 16 + m] : 0.f;
#pragma unroll
    for (int i = 0; i < 2; i++)
#pragma unroll
        for (int r = 0; r < 4; r++) {
            long n = n0 + wave * 32 + i * 16 + quad * 4 + r;
#pragma unroll
            for (int j = 0; j < 2; j++)
                atomicAdd(&off[n * 32 + j * 16 + m], acc[i][j][r] + tb[j]);
        }
}

// ---------------------------------------------------------------------------
// K3: bilinear sampling from bf16 h1 -> S bf16 [n][k], k = kk*96 + c.
// ---------------------------------------------------------------------------
__global__ __launch_bounds__(384) void k3_sample(
    const unsigned short* __restrict__ h1, const float* __restrict__ off,
    unsigned short* __restrict__ S)
{
    const int p = blockIdx.x;     // 0..195
    const int b = blockIdx.y;     // 0..63
    const int y = p / 14, xo = p % 14;
    const int tid = threadIdx.x;
    const int c4 = tid % 24, kk = tid / 24;
    const int kh = kk >> 2, kw = kk & 3;

    const float* ob = off + ((long)(b * 196 + p)) * 32;
    float dy = ob[kk * 2];
    float dx = ob[kk * 2 + 1];

    float py = (float)(y * 4 + kh) + dy;
    float px = (float)(xo * 4 + kw) + dx;
    float y0f = floorf(py), x0f = floorf(px);
    float wy = py - y0f, wx = px - x0f;
    int y0 = (int)y0f, x0 = (int)x0f;
    int y1 = y0 + 1,  x1 = x0 + 1;

    float my0 = (y0 >= 0 && y0 < 56) ? 1.f : 0.f;
    float my1 = (y1 >= 0 && y1 < 56) ? 1.f : 0.f;
    float mx0 = (x0 >= 0 && x0 < 56) ? 1.f : 0.f;
    float mx1 = (x1 >= 0 && x1 < 56) ? 1.f : 0.f;
    int y0c = min(max(y0, 0), 55), y1c = min(max(y1, 0), 55);
    int x0c = min(max(x0, 0), 55), x1c = min(max(x1, 0), 55);

    const unsigned short* hb = h1 + (long)b * 56 * 56 * 96 + c4 * 4;
    ushort4v v00 = *(const ushort4v*)&hb[(y0c * 56 + x0c) * 96];
    ushort4v v01 = *(const ushort4v*)&hb[(y0c * 56 + x1c) * 96];
    ushort4v v10 = *(const ushort4v*)&hb[(y1c * 56 + x0c) * 96];
    ushort4v v11 = *(const ushort4v*)&hb[(y1c * 56 + x1c) * 96];

    float w00 = my0 * mx0 * (1.f - wy) * (1.f - wx);
    float w01 = my0 * mx1 * (1.f - wy) * wx;
    float w10 = my1 * mx0 * wy * (1.f - wx);
    float w11 = my1 * mx1 * wy * wx;

    ushort4v rr;
#pragma unroll
    for (int c = 0; c < 4; c++) {
        float v = bf2f(((unsigned short*)&v00)[c]) * w00
                + bf2f(((unsigned short*)&v01)[c]) * w01
                + bf2f(((unsigned short*)&v10)[c]) * w10
                + bf2f(((unsigned short*)&v11)[c]) * w11;
        ((unsigned short*)&rr)[c] = f2bf(v);
    }

    long n = (long)b * 196 + p;
    *(ushort4v*)&S[n * 1536 + kk * 96 + c4 * 4] = rr;
}

// ---------------------------------------------------------------------------
// K4: bf16 MFMA GEMM  C[n][oc] = S[n][k] * Wtb[oc][k]^T  (N=12544,M=768,K=1536)
// Geometry = r6 (proven correct): BM=BN=128, BK=64, 256 thr / 4 waves (2x2,
// per-wave 64x64), 64KB LDS dbuf, 2 blocks/CU, grid 588 XCD-swizzled,
// asm ds_read + XOR swizzle (conflict-free, r1-r6: BANK_CONFLICT==0).
// SCHEDULE FIX (r5/r6 invariant: ~1100cyc/phase while work is ~70cyc):
// r5/r6 issued tile t's last chunk only ONE phase before waiting on it ->
// exposed ~full HBM/L2 latency every tile; plus 8 barriers/tile.
// Now per tile:  (1) issue ALL 8 chunks of t+1 up-front -> vmcnt(8) waits
// on loads issued a FULL TILE ago (4x the lead);  (2) barriers cut 8 -> 2
// (intra-tile phases have no hazards: reads hit cb, writes hit nb; RAW
// covered by vmcnt+top-barrier, WAR by end-barrier);  (3) all 16 ds_reads
// issued up-front, MFMA clusters gated by counted lgkmcnt(6/4/2/0) (DS
// retires in-order) so LDS latency hides under the MFMA stream.
// ---------------------------------------------------------------------------
__global__ __launch_bounds__(256, 2) void k4_gemm_mfma(
    const unsigned short* __restrict__ S,    // [12544][1536] bf16
    const unsigned short* __restrict__ Wtb,  // [768][1536]  bf16 (B^T, scaled)
    const float* __restrict__ t2, float* __restrict__ out)
{
    const int tid  = threadIdx.x;
    const int wave = tid >> 6, lane = tid & 63;

    // bijective XCD swizzle for nwg=588: q=73, r=4
    int lid = blockIdx.x;
    int xcd = lid & 7, pos = lid >> 3;
    int work = ((xcd < 4) ? xcd * 74 : 296 + (xcd - 4) * 73) + pos;
    const int n0  = (work / 6) * 128;
    const int oc0 = (work % 6) * 128;

    const int wr = wave >> 1, wc = wave & 1;     // 2 x 2 wave grid
    const int m = lane & 15, quad = lane >> 4;

    __shared__ unsigned short sA[2][8192];       // [buf][128 rows * 64 k] 32KB
    __shared__ unsigned short sB[2][8192];       // [buf][128 rows * 64 k] 32KB

    // staging: one gload_lds = 64 lanes x 16B = 8 rows of 128B.
    // lane -> row lr = lane>>3, slot ls = lane&7; LDS slot s of row r holds
    // logical k-chunk s^(r&7); source fetches chunk ls^lr.
    const int lr = lane >> 3;
    const int ls = lane & 7;
    const int swzk = ((ls ^ lr) * 8);            // element offset in 64-k row

    // 4 chunks/K-tile: A rows [0,64), [64,128), B rows [0,64), [64,128).
    // chunk = 8KB = 8 instrs = 2 per wave (rows wave*16 + {0,8}).
    const unsigned short* pA0  = S   + (long)(n0  + wave * 16 + lr) * 1536 + swzk;
    const unsigned short* pA0b = pA0 + 8 * 1536;
    const unsigned short* pA1  = pA0 + 64 * 1536;
    const unsigned short* pA1b = pA1 + 8 * 1536;
    const unsigned short* pB0  = Wtb + (long)(oc0 + wave * 16 + lr) * 1536 + swzk;
    const unsigned short* pB0b = pB0 + 8 * 1536;
    const unsigned short* pB1  = pB0 + 64 * 1536;
    const unsigned short* pB1b = pB1 + 8 * 1536;

    const int ldsO0  = wave * 1024;              // (wave*16)*64
    const int ldsO0b = wave * 1024 + 512;        // (wave*16+8)*64
    const int ldsO1  = 4096 + wave * 1024;       // (64+wave*16)*64
    const int ldsO1b = 4096 + wave * 1024 + 512;

    auto gl = [&](const unsigned short* g, unsigned short* l) {
        __builtin_amdgcn_global_load_lds(
            (const __attribute__((address_space(1))) void*)g,
            (__attribute__((address_space(3))) void*)l, 16, 0, 0);
    };
    // issue all 8 chunks of a tile into buffer nb (A-lo, A-hi, B-lo, B-hi)
    auto stage_tile = [&](int nb) {
        gl(pA0, &sA[nb][ldsO0]); gl(pA0b, &sA[nb][ldsO0b]); pA0 += 64; pA0b += 64;
        gl(pA1, &sA[nb][ldsO1]); gl(pA1b, &sA[nb][ldsO1b]); pA1 += 64; pA1b += 64;
        gl(pB0, &sB[nb][ldsO0]); gl(pB0b, &sB[nb][ldsO0b]); pB0 += 64; pB0b += 64;
        gl(pB1, &sB[nb][ldsO1]); gl(pB1b, &sB[nb][ldsO1b]); pB1 += 64; pB1b += 64;
    };

    // per-thread fragment addressing (swizzled read): logical chunk
    // (ks*4+quad) of row r lives at slot ^(r&7); r&7 == m&7.
    const int rowA = (wr * 64 + m) * 64;
    const int rowB = (wc * 64 + m) * 64;
    const int x0 = ((quad)     ^ (m & 7)) * 8;   // ks = 0
    const int x1 = ((quad + 4) ^ (m & 7)) * 8;   // ks = 1

    floatx4 acc[4][4];
#pragma unroll
    for (int i = 0; i < 4; i++)
#pragma unroll
        for (int j = 0; j < 4; j++) acc[i][j] = (floatx4)0.f;

    // prologue: stage tile 0 (8 instr/wave in flight)
    stage_tile(0);

#define MFMA_PHASE(I, A0, A1)                                                 \
    __builtin_amdgcn_s_setprio(1);                                            \
    _Pragma("unroll")                                                         \
    for (int j = 0; j < 4; j++) {                                             \
        acc[(I)][j] = mfma16(A0, bfr[j][0], acc[(I)][j]);                     \
        acc[(I)][j] = mfma16(A1, bfr[j][1], acc[(I)][j]);                     \
    }                                                                         \
    __builtin_amdgcn_s_setprio(0);

    for (int t = 0; t < 24; ++t) {
        const int cb = t & 1, nb = cb ^ 1;
        const lds_us* pAk0 = (const lds_us*)(sA[cb]) + rowA + x0;
        const lds_us* pAk1 = (const lds_us*)(sA[cb]) + rowA + x1;
        const lds_us* pBk0 = (const lds_us*)(sB[cb]) + rowB + x0;
        const lds_us* pBk1 = (const lds_us*)(sB[cb]) + rowB + x1;

        // issue ALL of tile t+1 (writes nb; safe: end-barrier of t-1 passed),
        // then wait only for tile t's 8 loads (issued a full tile ago).
        if (t < 23) {
            stage_tile(nb);
            asm volatile("s_waitcnt vmcnt(8)" ::: "memory");
        } else {
            asm volatile("s_waitcnt vmcnt(0)" ::: "memory");
        }
        __builtin_amdgcn_sched_barrier(0);
        __builtin_amdgcn_s_barrier();            // RAW: every wave's tile-t loads landed

        // all 16 ds_reads up-front; DS retires in-order -> counted lgkmcnt
        bf16x8 bfr[4][2];
#pragma unroll
        for (int j = 0; j < 4; j++) {
            bfr[j][0] = ldsr(pBk0 + j * 1024);
            bfr[j][1] = ldsr(pBk1 + j * 1024);
        }
        bf16x8 a0_0 = ldsr(pAk0);
        bf16x8 a0_1 = ldsr(pAk1);
        bf16x8 a1_0 = ldsr(pAk0 + 1024);
        bf16x8 a1_1 = ldsr(pAk1 + 1024);
        bf16x8 a2_0 = ldsr(pAk0 + 2 * 1024);
        bf16x8 a2_1 = ldsr(pAk1 + 2 * 1024);
        bf16x8 a3_0 = ldsr(pAk0 + 3 * 1024);
        bf16x8 a3_1 = ldsr(pAk1 + 3 * 1024);

        asm volatile("s_waitcnt lgkmcnt(6)" ::: "memory");   // B(8)+A0(2) done
        __builtin_amdgcn_sched_barrier(0);
        MFMA_PHASE(0, a0_0, a0_1)
        asm volatile("s_waitcnt lgkmcnt(4)" ::: "memory");   // +A1
        __builtin_amdgcn_sched_barrier(0);
        MFMA_PHASE(1, a1_0, a1_1)
        asm volatile("s_waitcnt lgkmcnt(2)" ::: "memory");   // +A2
        __builtin_amdgcn_sched_barrier(0);
        MFMA_PHASE(2, a2_0, a2_1)
        asm volatile("s_waitcnt lgkmcnt(0)" ::: "memory");   // +A3
        __builtin_amdgcn_sched_barrier(0);
        MFMA_PHASE(3, a3_0, a3_1)

        __builtin_amdgcn_s_barrier();            // WAR: cb reads done before t+1
    }
#undef MFMA_PHASE

    // epilogue: bias + leaky-relu + store (f32, coalesced over m)
    float tb[4];
#pragma unroll
    for (int j = 0; j < 4; j++) tb[j] = t2[oc0 + wc * 64 + j * 16 + m];
#pragma unroll
    for (int i = 0; i < 4; i++) {
#pragma unroll
        for (int r = 0; r < 4; r++) {
            long n = n0 + wr * 64 + i * 16 + quad * 4 + r;
            float* orow = out + n * 768 + oc0 + wc * 64 + m;
#pragma unroll
            for (int j = 0; j < 4; j++) {
                float v = acc[i][j][r] + tb[j];
                orow[j * 16] = v >= 0.f ? v : SLOPE * v;
            }
        }
    }
}

// ---------------------------------------------------------------------------
extern "C" void kernel_launch(void* const* d_in, const int* in_sizes, int n_in,
                              void* d_out, int out_size, void* d_ws, size_t ws_size,
                              hipStream_t stream)
{
    const float* x      = (const float*)d_in[0];
    const float* stem_w = (const float*)d_in[1];
    const float* stem_b = (const float*)d_in[2];
    const float* bn1_g  = (const float*)d_in[3];
    const float* bn1_b  = (const float*)d_in[4];
    const float* bn1_m  = (const float*)d_in[5];
    const float* bn1_v  = (const float*)d_in[6];
    const float* off_w  = (const float*)d_in[7];
    const float* off_b  = (const float*)d_in[8];
    const float* dcn_w  = (const float*)d_in[9];
    const float* dcn_b  = (const float*)d_in[10];
    const float* bn2_g  = (const float*)d_in[11];
    const float* bn2_b  = (const float*)d_in[12];
    const float* bn2_m  = (const float*)d_in[13];
    const float* bn2_v  = (const float*)d_in[14];

    float* ws  = (float*)d_ws;        // needs 81.2 MB
    float* out = (float*)d_out;

    unsigned short* h1  = (unsigned short*)(ws + WS_H1B);
    float* off = ws + WS_OFF;
    float* s1  = ws + WS_S1;
    float* t1  = ws + WS_T1;
    float* t2  = ws + WS_T2;
    unsigned short* Sb  = (unsigned short*)(ws + WS_SB);
    unsigned short* Wtb = (unsigned short*)(ws + WS_WTB);
    unsigned short* Wob = (unsigned short*)(ws + WS_WOB);
    unsigned short* W1b = (unsigned short*)(ws + WS_W1B);

    // k0 also zeroes the atomic `off` buffer (blocks 801..1192)
    k0_prep<<<1193, 256, 0, stream>>>(stem_w, stem_b, bn1_g, bn1_b, bn1_m, bn1_v,
                                      off_w, dcn_w, dcn_b, bn2_g, bn2_b, bn2_m,
                                      bn2_v, ws);
    k1_stem_mfma<<<1568, 256, 0, stream>>>(x, W1b, s1, t1, h1);
    k2_mfma<<<392, 256, 0, stream>>>(h1, Wob, off_b, off);
    k3_sample<<<dim3(196, 64), 384, 0, stream>>>(h1, off, Sb);
    k4_gemm_mfma<<<588, 256, 0, stream>>>(Sb, Wtb, t2, out);
}

// Round 8
// 189.234 us; speedup vs baseline: 1.0975x; 1.0341x over previous
//
#include <hip/hip_runtime.h>

#define EPS   1e-5f
#define SLOPE 0.01f

// ---------------------------------------------------------------------------
// Workspace layout (float offsets). Total 20,287,424 floats = 81.1 MB.
// ---------------------------------------------------------------------------
#define WS_H1B  0L            // h1  bf16 NHWC (64,56,56,96)   (9633792 f)
#define WS_OFF  9633792L      // off f32 [n=12544][32]            401408
#define WS_S1   10035200L     // bn1 scale f32 [96]
#define WS_T1   10035296L     // bn1 bias  f32 [96]
#define WS_T2   10035392L     // fused dcn_b+bn2 bias f32 [768]
#define WS_SB   10036160L     // S   bf16 [n=12544][k=1536]    (9633792 f)
#define WS_WTB  19669952L     // Wtb bf16 [oc=768][k=1536]      (589824 f)
#define WS_WOB  20259776L     // Wob bf16 [oc=32][k=1536]        (24576 f)
#define WS_W1B  20284352L     // W1b bf16 [ks=2][oc=96][kl=32]    (3072 f)

__device__ __forceinline__ unsigned short f2bf(float f) {
    unsigned int u = __builtin_bit_cast(unsigned int, f);
    u += 0x7fffu + ((u >> 16) & 1u);
    return (unsigned short)(u >> 16);
}
__device__ __forceinline__ float bf2f(unsigned short u) {
    unsigned int t = ((unsigned int)u) << 16;
    return __builtin_bit_cast(float, t);
}

typedef __attribute__((ext_vector_type(4))) unsigned short ushort4v;
typedef __attribute__((ext_vector_type(8))) unsigned short ushort8v;
typedef __attribute__((ext_vector_type(8))) short bf16x8;
typedef __attribute__((ext_vector_type(4))) float floatx4;

__device__ __forceinline__ floatx4 mfma16(bf16x8 a, bf16x8 b, floatx4 c) {
    return __builtin_amdgcn_mfma_f32_16x16x32_bf16(a, b, c, 0, 0, 0);
}

// LDS pointer type (32-bit AS3) + inline-asm ds_read_b128 the compiler's
// alias analysis can't see (so it cannot insert its own vmcnt drains --
// ordering is handled by OUR vmcnt/lgkmcnt asm + barriers; rule #18).
// PROVEN r5: this removed the compiler drain, k4 60.3 -> 50.5 us.
typedef __attribute__((address_space(3))) unsigned short lds_us;
__device__ __forceinline__ bf16x8 ldsr(const lds_us* p) {
    bf16x8 r;
    asm volatile("ds_read_b128 %0, %1" : "=&v"(r) : "v"(p));
    return r;
}

// ---------------------------------------------------------------------------
// K0: weight prep, transpose-via-LDS for coalescing.
// blk <800: Wtb/Wob transpose. blk==800: W1b/s1/t1/t2. blk>800 (392 blocks):
// zero the atomic `off` buffer (folds the hipMemsetAsync dispatch away).
// ---------------------------------------------------------------------------
__global__ __launch_bounds__(256) void k0_prep(
    const float* __restrict__ stem_w, const float* __restrict__ stem_b,
    const float* __restrict__ bn1_g,  const float* __restrict__ bn1_b,
    const float* __restrict__ bn1_m,  const float* __restrict__ bn1_v,
    const float* __restrict__ off_w,  const float* __restrict__ dcn_w,
    const float* __restrict__ dcn_b,  const float* __restrict__ bn2_g,
    const float* __restrict__ bn2_b,  const float* __restrict__ bn2_m,
    const float* __restrict__ bn2_v,  float* __restrict__ ws)
{
    const int tid = threadIdx.x;
    const int blk = blockIdx.x;
    unsigned short* Wtb = (unsigned short*)(ws + WS_WTB);
    unsigned short* Wob = (unsigned short*)(ws + WS_WOB);
    unsigned short* W1b = (unsigned short*)(ws + WS_W1B);

    if (blk < 800) {
        __shared__ float row[1536];
        const int oc = (blk < 768) ? blk : blk - 768;
        const float* src = (blk < 768) ? (dcn_w + (long)oc * 1536)
                                       : (off_w + (long)oc * 1536);
        for (int i = tid; i < 1536; i += 256) row[i] = src[i];
        float sc = 1.f;
        if (blk < 768) sc = bn2_g[oc] * rsqrtf(bn2_v[oc] + EPS);
        __syncthreads();
        if (tid < 192) {
            int k0 = tid * 8;
            ushort8v o;
#pragma unroll
            for (int t = 0; t < 8; t++) {
                int k = k0 + t;
                int kk = k / 96, c = k % 96;      // k = kk*96 + c
                ((unsigned short*)&o)[t] = f2bf(row[c * 16 + kk] * sc);
            }
            unsigned short* dst = (blk < 768) ? (Wtb + (long)oc * 1536 + k0)
                                              : (Wob + (long)oc * 1536 + k0);
            *(ushort8v*)dst = o;
        }
    } else if (blk == 800) {
        for (int i = tid; i < 6144; i += 256) {
            int ks = i / 3072, rr = i % 3072;
            int oc = rr >> 5, kl = rr & 31;
            int k = ks * 32 + kl;
            W1b[i] = f2bf(k < 48 ? stem_w[oc * 48 + k] : 0.f);
        }
        if (tid < 96) {
            float s = bn1_g[tid] * rsqrtf(bn1_v[tid] + EPS);
            ws[WS_S1 + tid] = s;
            ws[WS_T1 + tid] = stem_b[tid] * s + bn1_b[tid] - bn1_m[tid] * s;
        }
        for (int i = tid; i < 768; i += 256) {
            float inv2 = bn2_g[i] * rsqrtf(bn2_v[i] + EPS);
            ws[WS_T2 + i] = dcn_b[i] * inv2 + bn2_b[i] - bn2_m[i] * inv2;
        }
    } else {
        // zero off: 392 blocks x 256 thr x 4 f = 401408 floats exactly
        long i = (long)(blk - 801) * 1024 + tid * 4;
        float4 z; z.x = 0.f; z.y = 0.f; z.z = 0.f; z.w = 0.f;
        *(float4*)&ws[WS_OFF + i] = z;
    }
}

// ---------------------------------------------------------------------------
// K1: stem conv as bf16 MFMA GEMM, coalesced staging + LDS-repacked stores.
// ---------------------------------------------------------------------------
__global__ __launch_bounds__(256) void k1_stem_mfma(
    const float* __restrict__ x, const unsigned short* __restrict__ W1b,
    const float* __restrict__ s1, const float* __restrict__ t1,
    unsigned short* __restrict__ h1)
{
    const int tid  = threadIdx.x;
    const int wave = tid >> 6, lane = tid & 63;
    const int m = lane & 15, quad = lane >> 4;
    const int p0 = blockIdx.x * 128;

    __shared__ unsigned short sm[14336];   // 28672 B
    unsigned short* sA = sm;               // [2][128][32]
    unsigned short* sB = sm + 8192;        // [2][96][32]

#pragma unroll
    for (int i = 0; i < 3; i++) {
        int inst = wave * 3 + i;
        const unsigned short* g = W1b + inst * 512 + lane * 8;
        __builtin_amdgcn_global_load_lds(
            (const __attribute__((address_space(1))) void*)g,
            (__attribute__((address_space(3))) void*)(sB + inst * 512), 16, 0, 0);
    }
    {
        int r = tid >> 1, off = 16 + (tid & 1) * 8;
        *(ushort8v*)&sA[4096 + r * 32 + off] = (ushort8v)0;
    }
#pragma unroll
    for (int i = 0; i < 6; i++) {
        int unit = i * 256 + tid;
        int r = unit & 127, s = unit >> 7;
        int ci = s >> 2, kh = s & 3;
        int p = p0 + r;
        int b = p / 3136, rem = p % 3136;
        int oy = rem / 56, ox = rem % 56;
        float4 v = *(const float4*)&x[((long)((b * 3 + ci) * 224 + oy * 4 + kh)) * 224 + ox * 4];
        ushort4v hv;
        hv.x = f2bf(v.x); hv.y = f2bf(v.y); hv.z = f2bf(v.z); hv.w = f2bf(v.w);
        int k0i = ci * 16 + kh * 4;
        *(ushort4v*)&sA[(k0i >> 5) * 4096 + r * 32 + (k0i & 31)] = hv;
    }
    __syncthreads();

    bf16x8 bfv[6][2], af[2][2];
#pragma unroll
    for (int j = 0; j < 6; j++)
#pragma unroll
        for (int ks = 0; ks < 2; ks++)
            bfv[j][ks] = *(const bf16x8*)&sB[ks * 3072 + (j * 16 + m) * 32 + quad * 8];
#pragma unroll
    for (int rt = 0; rt < 2; rt++)
#pragma unroll
        for (int ks = 0; ks < 2; ks++)
            af[rt][ks] = *(const bf16x8*)&sA[ks * 4096 + (wave * 32 + rt * 16 + m) * 32 + quad * 8];

    floatx4 acc[2][6];
#pragma unroll
    for (int rt = 0; rt < 2; rt++)
#pragma unroll
        for (int j = 0; j < 6; j++) {
            floatx4 a = (floatx4)0.f;
            a = __builtin_amdgcn_mfma_f32_16x16x32_bf16(af[rt][0], bfv[j][0], a, 0, 0, 0);
            a = __builtin_amdgcn_mfma_f32_16x16x32_bf16(af[rt][1], bfv[j][1], a, 0, 0, 0);
            acc[rt][j] = a;
        }

    __syncthreads();
#pragma unroll
    for (int j = 0; j < 6; j++) {
        int c = j * 16 + m;
        float sc = s1[c], bi = t1[c];
#pragma unroll
        for (int rt = 0; rt < 2; rt++)
#pragma unroll
            for (int r = 0; r < 4; r++) {
                int row = wave * 32 + rt * 16 + quad * 4 + r;
                float v = acc[rt][j][r] * sc + bi;
                v = v >= 0.f ? v : SLOPE * v;
                sm[row * 96 + c] = f2bf(v);
            }
    }
    __syncthreads();
#pragma unroll
    for (int i = 0; i < 6; i++) {
        int idx = (i * 256 + tid) * 8;
        *(ushort8v*)&h1[(long)p0 * 96 + idx] = *(const ushort8v*)&sm[idx];
    }
}

// ---------------------------------------------------------------------------
// K2: offset conv C[128n x 32oc], K-split x4 across blocks (ks = kh), now
// with the PROVEN r7 k4 schedule. Key identity: h1's (kw, c) dims are
// contiguous, so im2col k-index klocal = kw*96+c maps FLAT into h1:
// addr = h1 + pix*96 + ks*5376 + klocal. A-staging is therefore identical
// to k4's (pointer += 64/tile), XOR-swizzled (slot ^= row&7), BK=64,
// 6 K-tiles, uniform 5 gload_lds/wave/tile -> counted vmcnt(5), asm
// ds_read + lgkmcnt(0), 2 barriers/tile. Replaces the old drain-per-step
// 12x __syncthreads loop (the defect that cost k4 60%).
// off must be zeroed beforehand (k0); ks==0 partial adds off_b.
// ---------------------------------------------------------------------------
__global__ __launch_bounds__(256) void k2_mfma(
    const unsigned short* __restrict__ h1,   // bf16 NHWC
    const unsigned short* __restrict__ Wob,  // [32][1536] bf16
    const float* __restrict__ off_b, float* __restrict__ off)
{
    const int tid  = threadIdx.x;
    const int wave = tid >> 6, lane = tid & 63;
    const int m = lane & 15, quad = lane >> 4;
    const int nt = blockIdx.x % 98, ks = blockIdx.x / 98;
    const int n0 = nt * 128;

    __shared__ unsigned short sA[2][8192];   // [buf][128 rows * 64 k] 16KB
    __shared__ unsigned short sB[2][2048];   // [buf][ 32 rows * 64 k]  4KB

    const int lr = lane >> 3, ls = lane & 7;
    const int swzk = (ls ^ lr) * 8;

    // A: rows are pixels n0 + wave*32 + ti*8 + lr; flat k offset = ks*5376 + klocal
    const unsigned short* gA[4];
#pragma unroll
    for (int ti = 0; ti < 4; ti++) {
        int n = n0 + wave * 32 + ti * 8 + lr;
        int b = n / 196, pp = n % 196;
        long pix = ((long)(b * 56 + (pp / 14) * 4) * 56 + (pp % 14) * 4);
        gA[ti] = h1 + pix * 96 + (long)ks * 5376 + swzk;
    }
    // B: oc rows wave*8 + lr, k = ks*384 + klocal
    const unsigned short* gBp = Wob + (long)(wave * 8 + lr) * 1536 + ks * 384 + swzk;

    const int ldsA = (wave * 32) * 64;
    const int ldsB = (wave * 8) * 64;

    auto gl = [&](const unsigned short* g, unsigned short* l) {
        __builtin_amdgcn_global_load_lds(
            (const __attribute__((address_space(1))) void*)g,
            (__attribute__((address_space(3))) void*)l, 16, 0, 0);
    };
    auto stage = [&](int nb) {
#pragma unroll
        for (int ti = 0; ti < 4; ti++) {
            gl(gA[ti], &sA[nb][ldsA + ti * 512]);
            gA[ti] += 64;
        }
        gl(gBp, &sB[nb][ldsB]);
        gBp += 64;
    };

    floatx4 acc[2][2];
#pragma unroll
    for (int i = 0; i < 2; i++)
#pragma unroll
        for (int j = 0; j < 2; j++) acc[i][j] = (floatx4)0.f;

    const int rowA0 = (wave * 32 + m) * 64;
    const int rowA1 = (wave * 32 + 16 + m) * 64;
    const int rowB0 = m * 64;
    const int rowB1 = (16 + m) * 64;
    const int x0 = ((quad)     ^ (m & 7)) * 8;
    const int x1 = ((quad + 4) ^ (m & 7)) * 8;

    stage(0);
    for (int t = 0; t < 6; ++t) {
        const int cb = t & 1, nb = cb ^ 1;
        if (t < 5) {
            stage(nb);
            asm volatile("s_waitcnt vmcnt(5)" ::: "memory");
        } else {
            asm volatile("s_waitcnt vmcnt(0)" ::: "memory");
        }
        __builtin_amdgcn_sched_barrier(0);
        __builtin_amdgcn_s_barrier();        // RAW: tile t landed for all waves

        const lds_us* bA = (const lds_us*)sA[cb];
        const lds_us* bB = (const lds_us*)sB[cb];
        bf16x8 a00 = ldsr(bA + rowA0 + x0);
        bf16x8 a01 = ldsr(bA + rowA0 + x1);
        bf16x8 a10 = ldsr(bA + rowA1 + x0);
        bf16x8 a11 = ldsr(bA + rowA1 + x1);
        bf16x8 b00 = ldsr(bB + rowB0 + x0);
        bf16x8 b01 = ldsr(bB + rowB0 + x1);
        bf16x8 b10 = ldsr(bB + rowB1 + x0);
        bf16x8 b11 = ldsr(bB + rowB1 + x1);
        asm volatile("s_waitcnt lgkmcnt(0)" ::: "memory");
        __builtin_amdgcn_sched_barrier(0);
        __builtin_amdgcn_s_setprio(1);
        acc[0][0] = mfma16(a00, b00, acc[0][0]);
        acc[0][0] = mfma16(a01, b01, acc[0][0]);
        acc[0][1] = mfma16(a00, b10, acc[0][1]);
        acc[0][1] = mfma16(a01, b11, acc[0][1]);
        acc[1][0] = mfma16(a10, b00, acc[1][0]);
        acc[1][0] = mfma16(a11, b01, acc[1][0]);
        acc[1][1] = mfma16(a10, b10, acc[1][1]);
        acc[1][1] = mfma16(a11, b11, acc[1][1]);
        __builtin_amdgcn_s_setprio(0);
        __builtin_amdgcn_s_barrier();        // WAR: cb reads done before t+1 writes
    }

    float tb[2];
#pragma unroll
    for (int j = 0; j < 2; j++) tb[j] = (ks == 0) ? off_b[j * 16 + m] : 0.f;
#pragma unroll
    for (int i = 0; i < 2; i++)
#pragma unroll
        for (int r = 0; r < 4; r++) {
            long n = n0 + wave * 32 + i * 16 + quad * 4 + r;
#pragma unroll
            for (int j = 0; j < 2; j++)
                atomicAdd(&off[n * 32 + j * 16 + m], acc[i][j][r] + tb[j]);
        }
}

// ---------------------------------------------------------------------------
// K3: bilinear sampling from bf16 h1 -> S bf16 [n][k], k = kk*96 + c.
// Vectorized: 16B (ushort8v) loads/stores, 8 channels/thread (G13),
// 2 pixels per 384-thread block -> grid (98, 64), halved request count.
// ---------------------------------------------------------------------------
__global__ __launch_bounds__(384) void k3_sample(
    const unsigned short* __restrict__ h1, const float* __restrict__ off,
    unsigned short* __restrict__ S)
{
    const int tid = threadIdx.x;
    const int sub = tid / 192;            // 0..1 : pixel within block
    const int r   = tid % 192;
    const int c8  = r % 12, kk = r / 12;  // 8-ch group, kernel tap
    const int p = blockIdx.x * 2 + sub;   // 0..195
    const int b = blockIdx.y;             // 0..63
    const int y = p / 14, xo = p % 14;
    const int kh = kk >> 2, kw = kk & 3;

    const float* ob = off + ((long)(b * 196 + p)) * 32;
    float dy = ob[kk * 2];
    float dx = ob[kk * 2 + 1];

    float py = (float)(y * 4 + kh) + dy;
    float px = (float)(xo * 4 + kw) + dx;
    float y0f = floorf(py), x0f = floorf(px);
    float wy = py - y0f, wx = px - x0f;
    int y0 = (int)y0f, x0 = (int)x0f;
    int y1 = y0 + 1,  x1 = x0 + 1;

    float my0 = (y0 >= 0 && y0 < 56) ? 1.f : 0.f;
    float my1 = (y1 >= 0 && y1 < 56) ? 1.f : 0.f;
    float mx0 = (x0 >= 0 && x0 < 56) ? 1.f : 0.f;
    float mx1 = (x1 >= 0 && x1 < 56) ? 1.f : 0.f;
    int y0c = min(max(y0, 0), 55), y1c = min(max(y1, 0), 55);
    int x0c = min(max(x0, 0), 55), x1c = min(max(x1, 0), 55);

    const unsigned short* hb = h1 + (long)b * 301056 + c8 * 8;  // 56*56*96
    ushort8v v00 = *(const ushort8v*)&hb[(y0c * 56 + x0c) * 96];
    ushort8v v01 = *(const ushort8v*)&hb[(y0c * 56 + x1c) * 96];
    ushort8v v10 = *(const ushort8v*)&hb[(y1c * 56 + x0c) * 96];
    ushort8v v11 = *(const ushort8v*)&hb[(y1c * 56 + x1c) * 96];

    float w00 = my0 * mx0 * (1.f - wy) * (1.f - wx);
    float w01 = my0 * mx1 * (1.f - wy) * wx;
    float w10 = my1 * mx0 * wy * (1.f - wx);
    float w11 = my1 * mx1 * wy * wx;

    ushort8v rr;
#pragma unroll
    for (int c = 0; c < 8; c++) {
        float v = bf2f(((unsigned short*)&v00)[c]) * w00
                + bf2f(((unsigned short*)&v01)[c]) * w01
                + bf2f(((unsigned short*)&v10)[c]) * w10
                + bf2f(((unsigned short*)&v11)[c]) * w11;
        ((unsigned short*)&rr)[c] = f2bf(v);
    }

    long n = (long)b * 196 + p;
    *(ushort8v*)&S[n * 1536 + kk * 96 + c8 * 8] = rr;
}

// ---------------------------------------------------------------------------
// K4: bf16 MFMA GEMM  C[n][oc] = S[n][k] * Wtb[oc][k]^T  (N=12544,M=768,K=1536)
// UNCHANGED from r7 (proven 42.2us, MfmaUtil 25.7, conflicts 0, near the
// LDS-port structural ceiling for this tile): BM=BN=128, BK=64, 256 thr /
// 4 waves (2x2, per-wave 64x64), 64KB LDS dbuf, 2 blocks/CU, grid 588
// XCD-swizzled. Full-tile prefetch (all 8 chunks of t+1 up-front), counted
// vmcnt(8) (lead = 1 full tile), 2 barriers/tile, all 16 ds_reads up-front
// with counted lgkmcnt(6/4/2/0) gating MFMA clusters.
// ---------------------------------------------------------------------------
__global__ __launch_bounds__(256, 2) void k4_gemm_mfma(
    const unsigned short* __restrict__ S,    // [12544][1536] bf16
    const unsigned short* __restrict__ Wtb,  // [768][1536]  bf16 (B^T, scaled)
    const float* __restrict__ t2, float* __restrict__ out)
{
    const int tid  = threadIdx.x;
    const int wave = tid >> 6, lane = tid & 63;

    // bijective XCD swizzle for nwg=588: q=73, r=4
    int lid = blockIdx.x;
    int xcd = lid & 7, pos = lid >> 3;
    int work = ((xcd < 4) ? xcd * 74 : 296 + (xcd - 4) * 73) + pos;
    const int n0  = (work / 6) * 128;
    const int oc0 = (work % 6) * 128;

    const int wr = wave >> 1, wc = wave & 1;     // 2 x 2 wave grid
    const int m = lane & 15, quad = lane >> 4;

    __shared__ unsigned short sA[2][8192];       // [buf][128 rows * 64 k] 32KB
    __shared__ unsigned short sB[2][8192];       // [buf][128 rows * 64 k] 32KB

    const int lr = lane >> 3;
    const int ls = lane & 7;
    const int swzk = ((ls ^ lr) * 8);            // element offset in 64-k row

    const unsigned short* pA0  = S   + (long)(n0  + wave * 16 + lr) * 1536 + swzk;
    const unsigned short* pA0b = pA0 + 8 * 1536;
    const unsigned short* pA1  = pA0 + 64 * 1536;
    const unsigned short* pA1b = pA1 + 8 * 1536;
    const unsigned short* pB0  = Wtb + (long)(oc0 + wave * 16 + lr) * 1536 + swzk;
    const unsigned short* pB0b = pB0 + 8 * 1536;
    const unsigned short* pB1  = pB0 + 64 * 1536;
    const unsigned short* pB1b = pB1 + 8 * 1536;

    const int ldsO0  = wave * 1024;              // (wave*16)*64
    const int ldsO0b = wave * 1024 + 512;        // (wave*16+8)*64
    const int ldsO1  = 4096 + wave * 1024;       // (64+wave*16)*64
    const int ldsO1b = 4096 + wave * 1024 + 512;

    auto gl = [&](const unsigned short* g, unsigned short* l) {
        __builtin_amdgcn_global_load_lds(
            (const __attribute__((address_space(1))) void*)g,
            (__attribute__((address_space(3))) void*)l, 16, 0, 0);
    };
    auto stage_tile = [&](int nb) {
        gl(pA0, &sA[nb][ldsO0]); gl(pA0b, &sA[nb][ldsO0b]); pA0 += 64; pA0b += 64;
        gl(pA1, &sA[nb][ldsO1]); gl(pA1b, &sA[nb][ldsO1b]); pA1 += 64; pA1b += 64;
        gl(pB0, &sB[nb][ldsO0]); gl(pB0b, &sB[nb][ldsO0b]); pB0 += 64; pB0b += 64;
        gl(pB1, &sB[nb][ldsO1]); gl(pB1b, &sB[nb][ldsO1b]); pB1 += 64; pB1b += 64;
    };

    const int rowA = (wr * 64 + m) * 64;
    const int rowB = (wc * 64 + m) * 64;
    const int x0 = ((quad)     ^ (m & 7)) * 8;   // ks = 0
    const int x1 = ((quad + 4) ^ (m & 7)) * 8;   // ks = 1

    floatx4 acc[4][4];
#pragma unroll
    for (int i = 0; i < 4; i++)
#pragma unroll
        for (int j = 0; j < 4; j++) acc[i][j] = (floatx4)0.f;

    stage_tile(0);

#define MFMA_PHASE(I, A0, A1)                                                 \
    __builtin_amdgcn_s_setprio(1);                                            \
    _Pragma("unroll")                                                         \
    for (int j = 0; j < 4; j++) {                                             \
        acc[(I)][j] = mfma16(A0, bfr[j][0], acc[(I)][j]);                     \
        acc[(I)][j] = mfma16(A1, bfr[j][1], acc[(I)][j]);                     \
    }                                                                         \
    __builtin_amdgcn_s_setprio(0);

    for (int t = 0; t < 24; ++t) {
        const int cb = t & 1, nb = cb ^ 1;
        const lds_us* pAk0 = (const lds_us*)(sA[cb]) + rowA + x0;
        const lds_us* pAk1 = (const lds_us*)(sA[cb]) + rowA + x1;
        const lds_us* pBk0 = (const lds_us*)(sB[cb]) + rowB + x0;
        const lds_us* pBk1 = (const lds_us*)(sB[cb]) + rowB + x1;

        if (t < 23) {
            stage_tile(nb);
            asm volatile("s_waitcnt vmcnt(8)" ::: "memory");
        } else {
            asm volatile("s_waitcnt vmcnt(0)" ::: "memory");
        }
        __builtin_amdgcn_sched_barrier(0);
        __builtin_amdgcn_s_barrier();            // RAW: every wave's tile-t loads landed

        bf16x8 bfr[4][2];
#pragma unroll
        for (int j = 0; j < 4; j++) {
            bfr[j][0] = ldsr(pBk0 + j * 1024);
            bfr[j][1] = ldsr(pBk1 + j * 1024);
        }
        bf16x8 a0_0 = ldsr(pAk0);
        bf16x8 a0_1 = ldsr(pAk1);
        bf16x8 a1_0 = ldsr(pAk0 + 1024);
        bf16x8 a1_1 = ldsr(pAk1 + 1024);
        bf16x8 a2_0 = ldsr(pAk0 + 2 * 1024);
        bf16x8 a2_1 = ldsr(pAk1 + 2 * 1024);
        bf16x8 a3_0 = ldsr(pAk0 + 3 * 1024);
        bf16x8 a3_1 = ldsr(pAk1 + 3 * 1024);

        asm volatile("s_waitcnt lgkmcnt(6)" ::: "memory");   // B(8)+A0(2) done
        __builtin_amdgcn_sched_barrier(0);
        MFMA_PHASE(0, a0_0, a0_1)
        asm volatile("s_waitcnt lgkmcnt(4)" ::: "memory");   // +A1
        __builtin_amdgcn_sched_barrier(0);
        MFMA_PHASE(1, a1_0, a1_1)
        asm volatile("s_waitcnt lgkmcnt(2)" ::: "memory");   // +A2
        __builtin_amdgcn_sched_barrier(0);
        MFMA_PHASE(2, a2_0, a2_1)
        asm volatile("s_waitcnt lgkmcnt(0)" ::: "memory");   // +A3
        __builtin_amdgcn_sched_barrier(0);
        MFMA_PHASE(3, a3_0, a3_1)

        __builtin_amdgcn_s_barrier();            // WAR: cb reads done before t+1
    }
#undef MFMA_PHASE

    float tb[4];
#pragma unroll
    for (int j = 0; j < 4; j++) tb[j] = t2[oc0 + wc * 64 + j * 16 + m];
#pragma unroll
    for (int i = 0; i < 4; i++) {
#pragma unroll
        for (int r = 0; r < 4; r++) {
            long n = n0 + wr * 64 + i * 16 + quad * 4 + r;
            float* orow = out + n * 768 + oc0 + wc * 64 + m;
#pragma unroll
            for (int j = 0; j < 4; j++) {
                float v = acc[i][j][r] + tb[j];
                orow[j * 16] = v >= 0.f ? v : SLOPE * v;
            }
        }
    }
}

// ---------------------------------------------------------------------------
extern "C" void kernel_launch(void* const* d_in, const int* in_sizes, int n_in,
                              void* d_out, int out_size, void* d_ws, size_t ws_size,
                              hipStream_t stream)
{
    const float* x      = (const float*)d_in[0];
    const float* stem_w = (const float*)d_in[1];
    const float* stem_b = (const float*)d_in[2];
    const float* bn1_g  = (const float*)d_in[3];
    const float* bn1_b  = (const float*)d_in[4];
    const float* bn1_m  = (const float*)d_in[5];
    const float* bn1_v  = (const float*)d_in[6];
    const float* off_w  = (const float*)d_in[7];
    const float* off_b  = (const float*)d_in[8];
    const float* dcn_w  = (const float*)d_in[9];
    const float* dcn_b  = (const float*)d_in[10];
    const float* bn2_g  = (const float*)d_in[11];
    const float* bn2_b  = (const float*)d_in[12];
    const float* bn2_m  = (const float*)d_in[13];
    const float* bn2_v  = (const float*)d_in[14];

    float* ws  = (float*)d_ws;        // needs 81.2 MB
    float* out = (float*)d_out;

    unsigned short* h1  = (unsigned short*)(ws + WS_H1B);
    float* off = ws + WS_OFF;
    float* s1  = ws + WS_S1;
    float* t1  = ws + WS_T1;
    float* t2  = ws + WS_T2;
    unsigned short* Sb  = (unsigned short*)(ws + WS_SB);
    unsigned short* Wtb = (unsigned short*)(ws + WS_WTB);
    unsigned short* Wob = (unsigned short*)(ws + WS_WOB);
    unsigned short* W1b = (unsigned short*)(ws + WS_W1B);

    // k0 also zeroes the atomic `off` buffer (blocks 801..1192)
    k0_prep<<<1193, 256, 0, stream>>>(stem_w, stem_b, bn1_g, bn1_b, bn1_m, bn1_v,
                                      off_w, dcn_w, dcn_b, bn2_g, bn2_b, bn2_m,
                                      bn2_v, ws);
    k1_stem_mfma<<<1568, 256, 0, stream>>>(x, W1b, s1, t1, h1);
    k2_mfma<<<392, 256, 0, stream>>>(h1, Wob, off_b, off);
    k3_sample<<<dim3(98, 64), 384, 0, stream>>>(h1, off, Sb);
    k4_gemm_mfma<<<588, 256, 0, stream>>>(Sb, Wtb, t2, out);
}